// Round 1
// baseline (299.915 us; speedup 1.0000x reference)
//
#include <hip/hip_runtime.h>

#define BATCH 8192
#define NCOL  4096

// logaddexp with sentinel-safe identity: lae(-3e38, x) == x exactly
// (d ~ 3e38 finite, __expf(-3e38)=0, log(1)=0, max=x).
__device__ __forceinline__ float lae(float a, float b) {
    float mx = fmaxf(a, b);
    float d  = fabsf(a - b);
    return mx + __logf(1.0f + __expf(-d));
}

__global__ void listmle_zero(double* acc) { acc[0] = 0.0; }

__global__ __launch_bounds__(256) void listmle_main(
        const float* __restrict__ outputs,
        const int*   __restrict__ labels,
        double*      __restrict__ acc) {
    __shared__ float row[NCOL];     // staged outputs row (16 KB)
    __shared__ float wtot[4];       // per-wave scan totals
    __shared__ float wsum[4];       // per-wave partial sums

    const int t    = threadIdx.x;
    const int lane = t & 63;
    const int wid  = t >> 6;
    const size_t base = (size_t)blockIdx.x * NCOL;

    // ---- Phase 1: issue row loads + label loads early, stage row in LDS ----
    const float4* o4 = (const float4*)(outputs + base);
    const int4*   l4 = (const int4*)(labels + base);
    float4* r4 = (float4*)row;

    float4 v[4];
#pragma unroll
    for (int k = 0; k < 4; ++k) v[k] = o4[k * 256 + t];
    int4 lb[4];
#pragma unroll
    for (int k = 0; k < 4; ++k) lb[k] = l4[4 * t + k];   // elems 16t .. 16t+15

    float sum_out = 0.f;
#pragma unroll
    for (int k = 0; k < 4; ++k) {
        r4[k * 256 + t] = v[k];
        sum_out += (v[k].x + v[k].y) + (v[k].z + v[k].w);
    }
    __syncthreads();

    // ---- Phase 2: gather own 16 contiguous elems, local inclusive scan ----
    float l[16];
    float r = 0.f;
#pragma unroll
    for (int k = 0; k < 4; ++k) {
        float g0 = row[lb[k].x];
        float g1 = row[lb[k].y];
        float g2 = row[lb[k].z];
        float g3 = row[lb[k].w];
        if (k == 0) r = g0; else r = lae(r, g0);
        l[4 * k + 0] = r;
        r = lae(r, g1); l[4 * k + 1] = r;
        r = lae(r, g2); l[4 * k + 2] = r;
        r = lae(r, g3); l[4 * k + 3] = r;
    }
    // r = LSE of this thread's chunk (elements 16t .. 16t+15)

    // ---- Phase 3: wave inclusive scan of chunk totals ----
    const float NEG = -3.0e38f;
    float p = r;
#pragma unroll
    for (int off = 1; off < 64; off <<= 1) {
        float o = __shfl_up(p, off, 64);
        if (lane >= off) p = lae(p, o);
    }
    if (lane == 63) wtot[wid] = p;      // wave total
    float ep = __shfl_up(p, 1, 64);     // exclusive lane prefix
    if (lane == 0) ep = NEG;
    __syncthreads();

    float wexc = NEG;                   // exclusive wave prefix
#pragma unroll
    for (int w = 0; w < 3; ++w)
        if (w < wid) wexc = lae(wexc, wtot[w]);
    float P = lae(wexc, ep);            // full exclusive prefix for this thread

    // ---- Phase 4: scores and reduction ----
    float ssum = 0.f;
#pragma unroll
    for (int j = 0; j < 16; ++j) ssum += lae(P, l[j]);

    float part = ssum - sum_out;
#pragma unroll
    for (int off = 32; off; off >>= 1) part += __shfl_down(part, off, 64);
    if (lane == 0) wsum[wid] = part;
    __syncthreads();
    if (t == 0) {
        double tot = ((double)wsum[0] + (double)wsum[1]) +
                     ((double)wsum[2] + (double)wsum[3]);
        atomicAdd(acc, tot);
    }
}

__global__ void listmle_finalize(const double* __restrict__ acc,
                                 float* __restrict__ out) {
    out[0] = (float)(acc[0] * (1.0 / ((double)BATCH * (double)NCOL)));
}

extern "C" void kernel_launch(void* const* d_in, const int* in_sizes, int n_in,
                              void* d_out, int out_size, void* d_ws, size_t ws_size,
                              hipStream_t stream) {
    const float* outputs = (const float*)d_in[0];
    const int*   labels  = (const int*)d_in[1];
    double* acc = (double*)d_ws;      // 8 bytes of scratch
    float*  out = (float*)d_out;

    listmle_zero<<<1, 1, 0, stream>>>(acc);
    listmle_main<<<BATCH, 256, 0, stream>>>(outputs, labels, acc);
    listmle_finalize<<<1, 1, 0, stream>>>(acc, out);
}

// Round 2
// 273.991 us; speedup vs baseline: 1.0946x; 1.0946x over previous
//
#include <hip/hip_runtime.h>

#define BATCH 8192
#define NCOL  4096

// logaddexp with sentinel-safe identity: lae(-3e38, x) == x
__device__ __forceinline__ float lae(float a, float b) {
    float mx = fmaxf(a, b);
    float d  = fabsf(a - b);
    return mx + __logf(1.0f + __expf(-d));
}

__global__ __launch_bounds__(256) void listmle_main(
        const float* __restrict__ outputs,
        const int*   __restrict__ labels,
        double*      __restrict__ partial) {
    __shared__ float row[NCOL];     // staged outputs row (16 KB)
    __shared__ float wtot[4];       // per-wave scan totals (log domain)
    __shared__ float wsum[4];       // per-wave partial sums

    const int t    = threadIdx.x;
    const int lane = t & 63;
    const int wid  = t >> 6;
    const size_t base = (size_t)blockIdx.x * NCOL;
    const float NEG = -3.0e38f;

    // ---- Phase 1: stage row into LDS, labels into registers ----
    const float4* o4 = (const float4*)(outputs + base);
    const int4*   l4 = (const int4*)(labels + base);
    float4* r4 = (float4*)row;

    float4 v[4];
#pragma unroll
    for (int k = 0; k < 4; ++k) v[k] = o4[k * 256 + t];
    int4 lb[4];
#pragma unroll
    for (int k = 0; k < 4; ++k) lb[k] = l4[4 * t + k];   // elems 16t..16t+15

    float sum_out = 0.f;
#pragma unroll
    for (int k = 0; k < 4; ++k) {
        r4[k * 256 + t] = v[k];
        sum_out += (v[k].x + v[k].y) + (v[k].z + v[k].w);
    }
    __syncthreads();

    // ---- Phase 2: gather own 16 elems; max-shifted exp prefix sums ----
    float g[16];
#pragma unroll
    for (int k = 0; k < 4; ++k) {
        g[4 * k + 0] = row[lb[k].x];
        g[4 * k + 1] = row[lb[k].y];
        g[4 * k + 2] = row[lb[k].z];
        g[4 * k + 3] = row[lb[k].w];
    }
    // chunk max (tree)
    float m01 = fmaxf(fmaxf(g[0], g[1]),  fmaxf(g[2], g[3]));
    float m23 = fmaxf(fmaxf(g[4], g[5]),  fmaxf(g[6], g[7]));
    float m45 = fmaxf(fmaxf(g[8], g[9]),  fmaxf(g[10], g[11]));
    float m67 = fmaxf(fmaxf(g[12], g[13]), fmaxf(g[14], g[15]));
    float m = fmaxf(fmaxf(m01, m23), fmaxf(m45, m67));

    // independent exps, cheap fadd prefix chain
    float s[16];
    float run = 0.f;
#pragma unroll
    for (int i = 0; i < 16; ++i) {
        run += __expf(g[i] - m);
        s[i] = run;
    }
    float T = m + __logf(run);   // chunk LSE (run >= 1, safe)

    // ---- Phase 3: wave inclusive lae-scan of chunk totals ----
    float p = T;
#pragma unroll
    for (int off = 1; off < 64; off <<= 1) {
        float o = __shfl_up(p, off, 64);
        if (lane >= off) p = lae(p, o);
    }
    if (lane == 63) wtot[wid] = p;      // wave total
    float ep = __shfl_up(p, 1, 64);     // exclusive lane prefix
    if (lane == 0) ep = NEG;
    __syncthreads();

    float wexc = NEG;                   // exclusive wave prefix
#pragma unroll
    for (int w = 0; w < 3; ++w)
        if (w < wid) wexc = lae(wexc, wtot[w]);
    float P = lae(wexc, ep);            // full exclusive prefix (log domain)

    // ---- Phase 4: sum of scores via single log of a product ----
    // score_j = m' + log(a + b*s_j);  sum_j score_j = 16*m' + log(prod_j c_j)
    float mp = fmaxf(P, m);
    float a  = __expf(P - mp);          // 0 when P is the -3e38 sentinel
    float b  = __expf(m - mp);
    float pr0 = 1.f, pr1 = 1.f;         // each <= 17^8 ~ 7e9; product < 5e19
#pragma unroll
    for (int i = 0; i < 16; i += 2) {
        pr0 *= fmaf(b, s[i],     a);
        pr1 *= fmaf(b, s[i + 1], a);
    }
    float ssum = 16.f * mp + __logf(pr0 * pr1);

    // ---- Phase 5: block reduction, one partial per block ----
    float part = ssum - sum_out;
#pragma unroll
    for (int off = 32; off; off >>= 1) part += __shfl_down(part, off, 64);
    if (lane == 0) wsum[wid] = part;
    __syncthreads();
    if (t == 0) {
        partial[blockIdx.x] =
            (double)((wsum[0] + wsum[1]) + (wsum[2] + wsum[3]));
    }
}

__global__ __launch_bounds__(1024) void listmle_reduce(
        const double* __restrict__ partial, float* __restrict__ out) {
    __shared__ double sh[16];
    double s = 0.0;
    for (int i = threadIdx.x; i < BATCH; i += 1024) s += partial[i];
#pragma unroll
    for (int off = 32; off; off >>= 1) s += __shfl_down(s, off, 64);
    const int lane = threadIdx.x & 63, wid = threadIdx.x >> 6;
    if (lane == 0) sh[wid] = s;
    __syncthreads();
    if (threadIdx.x == 0) {
        double tot = 0.0;
#pragma unroll
        for (int w = 0; w < 16; ++w) tot += sh[w];
        out[0] = (float)(tot * (1.0 / ((double)BATCH * (double)NCOL)));
    }
}

extern "C" void kernel_launch(void* const* d_in, const int* in_sizes, int n_in,
                              void* d_out, int out_size, void* d_ws, size_t ws_size,
                              hipStream_t stream) {
    const float* outputs = (const float*)d_in[0];
    const int*   labels  = (const int*)d_in[1];
    double* partial = (double*)d_ws;    // BATCH doubles = 64 KB scratch
    float*  out     = (float*)d_out;

    listmle_main<<<BATCH, 256, 0, stream>>>(outputs, labels, partial);
    listmle_reduce<<<1, 1024, 0, stream>>>(partial, out);
}